// Round 1
// baseline (323.665 us; speedup 1.0000x reference)
//
#include <hip/hip_runtime.h>
#include <hip/hip_bf16.h>

// Problem constants (fixed by reference)
#define L_SEQ 1024
#define B_DLG 128
#define D_DIM 256
#define BM 64          // rows per block tile
#define THREADS 512    // 8 waves
#define KSTEPS 8       // 256 / 32

typedef __attribute__((ext_vector_type(8))) short short8;   // 8 bf16 (4 VGPRs)
typedef __attribute__((ext_vector_type(4))) float f32x4;    // MFMA accumulator

__device__ __forceinline__ float bfbits_to_f(unsigned short u) {
    return __uint_as_float(((unsigned int)u) << 16);
}
__device__ __forceinline__ unsigned short f_to_bfbits(float f) {
    unsigned int u = __float_as_uint(f);
    unsigned int r = (u + 0x7FFFu + ((u >> 16) & 1u)) >> 16;   // RNE
    return (unsigned short)r;
}
__device__ __forceinline__ float fast_tanh(float x) {
    // stable: x->+inf => 1, x->-inf => -1
    return 1.0f - 2.0f / (__expf(2.0f * x) + 1.0f);
}
__device__ __forceinline__ float fast_sigmoid(float x) {
    return 1.0f / (1.0f + __expf(-x));
}

// Convert the three (256x256) fp32 modality weights to bf16 bits in d_ws.
__global__ void wconv_kernel(const float* __restrict__ wa,
                             const float* __restrict__ wv,
                             const float* __restrict__ wl,
                             unsigned short* __restrict__ wb) {
    int i = blockIdx.x * blockDim.x + threadIdx.x;       // 0 .. 3*65536
    const float* src = (i < 65536) ? wa : (i < 131072 ? wv : wl);
    wb[i] = f_to_bfbits(src[i & 65535]);
}

__global__ __launch_bounds__(THREADS)
void fused_kernel(const float* __restrict__ a,
                  const float* __restrict__ v,
                  const float* __restrict__ l,
                  const unsigned short* __restrict__ wbf,   // [3][256][256] bf16 bits
                  const float* __restrict__ ba,
                  const float* __restrict__ bv,
                  const float* __restrict__ bl,
                  const float* __restrict__ wav, const float* __restrict__ bav,
                  const float* __restrict__ wal, const float* __restrict__ bal,
                  const float* __restrict__ wvl, const float* __restrict__ bvl,
                  float* __restrict__ out) {
    // LDS: 3 * 64 * 256 * 2B = 96 KiB (A tiles, XOR-swizzled rows)
    //      + gate weights 3*768*4 = 9 KiB + z 3*64*4
    __shared__ __align__(16) unsigned short lds_a[3][BM][D_DIM];
    __shared__ float lds_gw[3][3 * D_DIM];
    __shared__ float lds_z[3][BM];

    const int tid  = threadIdx.x;
    const int wave = tid >> 6;
    const int lane = tid & 63;
    const int bidx = blockIdx.x;
    const int b    = bidx >> 4;          // dialogue
    const int t0   = (bidx & 15) * BM;   // row-tile start within dialogue

    // ---------------- stage A tiles (fp32 -> bf16, swizzled) ----------------
    {
        const float* srcs[3] = {a, v, l};
#pragma unroll
        for (int mod = 0; mod < 3; ++mod) {
            const float* src = srcs[mod];
#pragma unroll
            for (int i = 0; i < 8; ++i) {
                int idx = tid + i * THREADS;     // 0 .. 4095
                int row = idx >> 6;              // 0 .. 63
                int c4  = idx & 63;              // float4 column
                const float4* p = (const float4*)(src +
                    ((size_t)(t0 + row) * B_DLG + b) * D_DIM + c4 * 4);
                float4 f = *p;
                ushort4 pk;
                pk.x = f_to_bfbits(f.x);
                pk.y = f_to_bfbits(f.y);
                pk.z = f_to_bfbits(f.z);
                pk.w = f_to_bfbits(f.w);
                int boff = (c4 * 8) ^ ((row & 7) << 4);   // XOR swizzle, 8B aligned
                *(ushort4*)((char*)&lds_a[mod][row][0] + boff) = pk;
            }
        }
        // gate weights -> LDS (fp32): [0]=Wav, [1]=Wal, [2]=Wvl
        for (int i = tid; i < 3 * 3 * D_DIM; i += THREADS) {
            int g = i / (3 * D_DIM);
            int k = i % (3 * D_DIM);
            const float* gw = (g == 0) ? wav : (g == 1) ? wal : wvl;
            lds_gw[g][k] = gw[k];
        }
    }
    __syncthreads();

    // ---------------- gates: z_av, z_al, z_vl per row (fp32 accum) ----------------
    {
        int gr = wave * 8 + (lane >> 3);   // row 0..63
        int kl = lane & 7;                 // 8 lanes per row
        float s0 = 0.f, s1 = 0.f, s2 = 0.f;
        const char* ra = (const char*)&lds_a[0][gr][0];
        const char* rv = (const char*)&lds_a[1][gr][0];
        const char* rl = (const char*)&lds_a[2][gr][0];
        int swz = (gr & 7) << 4;
#pragma unroll 4
        for (int j = 0; j < 32; ++j) {
            int k = kl * 32 + j;
            int bo = (k * 2) ^ swz;
            float xa = bfbits_to_f(*(const unsigned short*)(ra + bo));
            float xv = bfbits_to_f(*(const unsigned short*)(rv + bo));
            float xl = bfbits_to_f(*(const unsigned short*)(rl + bo));
            s0 += xa * lds_gw[0][k] + xv * lds_gw[0][256 + k] + xa * xv * lds_gw[0][512 + k];
            s1 += xa * lds_gw[1][k] + xl * lds_gw[1][256 + k] + xa * xl * lds_gw[1][512 + k];
            s2 += xv * lds_gw[2][k] + xl * lds_gw[2][256 + k] + xv * xl * lds_gw[2][512 + k];
        }
#pragma unroll
        for (int off = 1; off < 8; off <<= 1) {
            s0 += __shfl_xor(s0, off);
            s1 += __shfl_xor(s1, off);
            s2 += __shfl_xor(s2, off);
        }
        if (kl == 0) {
            lds_z[0][gr] = fast_sigmoid(s0 + bav[0]);
            lds_z[1][gr] = fast_sigmoid(s1 + bal[0]);
            lds_z[2][gr] = fast_sigmoid(s2 + bvl[0]);
        }
    }

    // ---------------- GEMM K-loop: 3 modalities, wave owns 32 cols ----------------
    f32x4 acc[3][4][2];
#pragma unroll
    for (int m = 0; m < 3; ++m)
#pragma unroll
        for (int mt = 0; mt < 4; ++mt)
#pragma unroll
            for (int ct = 0; ct < 2; ++ct)
                acc[m][mt][ct] = (f32x4){0.f, 0.f, 0.f, 0.f};

    const int colbase = wave * 32;
    const int l15 = lane & 15;
    const int kblk = lane >> 4;          // 0..3, each holds 8 of the 32 K elems

#pragma unroll 2
    for (int ks = 0; ks < KSTEPS; ++ks) {
        int kbyte = ks * 64 + kblk * 16;  // byte offset of this lane's 8 bf16 in a row
#pragma unroll
        for (int mod = 0; mod < 3; ++mod) {
            short8 afrag[4];
#pragma unroll
            for (int mt = 0; mt < 4; ++mt) {
                int row = mt * 16 + l15;
                int bo = kbyte ^ ((row & 7) << 4);
                afrag[mt] = *(const short8*)((const char*)&lds_a[mod][row][0] + bo);
            }
            const unsigned short* wmod = wbf + mod * 65536;
#pragma unroll
            for (int ct = 0; ct < 2; ++ct) {
                int col = colbase + ct * 16 + l15;
                short8 bfrag = *(const short8*)(wmod + col * D_DIM + ks * 32 + kblk * 8);
#pragma unroll
                for (int mt = 0; mt < 4; ++mt)
                    acc[mod][mt][ct] = __builtin_amdgcn_mfma_f32_16x16x32_bf16(
                        afrag[mt], bfrag, acc[mod][mt][ct], 0, 0, 0);
            }
        }
    }

    __syncthreads();   // z values visible to all waves

    // ---------------- epilogue: tanh + gated combine + store ----------------
    const size_t rowbase = (size_t)b * L_SEQ + t0;
#pragma unroll
    for (int mt = 0; mt < 4; ++mt) {
#pragma unroll
        for (int ct = 0; ct < 2; ++ct) {
            int col = colbase + ct * 16 + l15;
            float bba = ba[col], bbv = bv[col], bbl = bl[col];
#pragma unroll
            for (int r = 0; r < 4; ++r) {
                int rl_ = mt * 16 + (lane >> 4) * 4 + r;
                float ta = fast_tanh(acc[0][mt][ct][r] + bba);
                float tv = fast_tanh(acc[1][mt][ct][r] + bbv);
                float tl = fast_tanh(acc[2][mt][ct][r] + bbl);
                float zav = lds_z[0][rl_];
                float zal = lds_z[1][rl_];
                float zvl = lds_z[2][rl_];
                float* orow = out + (rowbase + rl_) * (3 * D_DIM);
                orow[col]             = zav * ta + (1.f - zav) * tv;
                orow[D_DIM + col]     = zal * ta + (1.f - zal) * tl;
                orow[2 * D_DIM + col] = zvl * tv + (1.f - zvl) * tl;
            }
        }
    }
}

extern "C" void kernel_launch(void* const* d_in, const int* in_sizes, int n_in,
                              void* d_out, int out_size, void* d_ws, size_t ws_size,
                              hipStream_t stream) {
    const float* a   = (const float*)d_in[0];
    const float* v   = (const float*)d_in[1];
    const float* l   = (const float*)d_in[2];
    // d_in[3] = lengths (all == L, static shape -> unused)
    const float* Wa  = (const float*)d_in[4];
    const float* ba  = (const float*)d_in[5];
    const float* Wv  = (const float*)d_in[6];
    const float* bv  = (const float*)d_in[7];
    const float* Wl  = (const float*)d_in[8];
    const float* bl  = (const float*)d_in[9];
    const float* Wav = (const float*)d_in[10];
    const float* bav = (const float*)d_in[11];
    const float* Wal = (const float*)d_in[12];
    const float* bal = (const float*)d_in[13];
    const float* Wvl = (const float*)d_in[14];
    const float* bvl = (const float*)d_in[15];
    float* out = (float*)d_out;

    unsigned short* wb = (unsigned short*)d_ws;   // needs 3*65536*2 = 384 KiB

    hipLaunchKernelGGL(wconv_kernel, dim3(768), dim3(256), 0, stream, Wa, Wv, Wl, wb);
    hipLaunchKernelGGL(fused_kernel, dim3(2048), dim3(THREADS), 0, stream,
                       a, v, l, wb, ba, bv, bl, Wav, bav, Wal, bal, Wvl, bvl, out);
}